// Round 6
// baseline (1772.340 us; speedup 1.0000x reference)
//
#include <hip/hip_runtime.h>

typedef __attribute__((ext_vector_type(8))) short bf16x8;   // 8 bf16 (4 VGPRs)
typedef __attribute__((ext_vector_type(4))) float f32x4;    // MFMA acc

#define NBATCH 64
#define NH     512
#define NV     8001
#define NVP    8064      // padded V (63 tiles of 128)
#define NSTEP  128       // T-1
#define NG     2048      // 4*NH gate columns
#define SLAB   32768     // NBATCH*NH ushorts = one 64KB step-slab

// ---- workspace layout (bytes) ----
// Write-once sequence slabs: no address is ever rewritten within a launch, so
// a consumer cache can never hold a stale copy; a cold miss fetches from the
// coherence point (local L2 for same-XCD producers, MALL for cross-XCD).
#define OFF_XS    ((size_t)0)
#define SZ_XS     ((size_t)NSTEP*SLAB*2)                 // 8 MB  bf16 [t][b][h]
#define OFF_WP    (OFF_XS + SZ_XS)
#define SZ_WP     ((size_t)2*2048*1024*2)                // 8 MB  frag-packed weights
#define OFF_WDEC  (OFF_WP + SZ_WP)
#define SZ_WDEC   ((size_t)NVP*NH*2)                     // 8.26 MB bf16, zero-padded rows
#define OFF_BIAS  (OFF_WDEC + SZ_WDEC)
#define SZ_BIAS   ((size_t)2*NG*4)                       // combined b_ih+b_hh per layer, fp32
#define OFF_H1    (OFF_BIAS + SZ_BIAS)
#define SZ_H1     ((size_t)(NSTEP+1)*SLAB*2)             // h1 after step t -> slot t+1 (slot 0 = zeros)
#define OFF_AB    (OFF_H1 + SZ_H1)
#define SZ_AB     ((size_t)NSTEP*SLAB*2)                 // a (post-BN1*mask1) at step t -> slot t
#define OFF_H2    (OFF_AB + SZ_AB)
#define SZ_H2     ((size_t)(NSTEP+1)*SLAB*2)             // h2 slots (slot 0 = zeros)
#define OFF_BSEQ  (OFF_H2 + SZ_H2)
#define SZ_BSEQ   ((size_t)NSTEP*SLAB*2)                 // 8 MB bf16 [t][b][h] (decoder input)
#define OFF_BAR   (OFF_BSEQ + SZ_BSEQ)
#define SZ_BAR    ((size_t)131072)                       // flags, 128B-strided

// flag indices (u32 units; 32 u32 = 128 B = one line per flag)
#define F_H1L(t)  ((t) * 32)               // XCD0-local: layer-0 arrivals, step t
#define F_H2L(t)  (4096 + (t) * 32)        // XCD1-local: layer-1 arrivals, step t
#define F_H1M(t)  (8192 + (t) * 32)        // MALL backup of F_H1L
#define F_H2M(t)  (12288 + (t) * 32)       // MALL backup of F_H2L
#define F_AB(t)   (16384 + (t) * 32)       // MALL: ab[t] published (layer-0 arrivals)
#define F_DC(c)   (20480 + (c) * 32)       // MALL: decode chunk c released (layer-1 arrivals)
#define F_QCNT    20608                    // MALL: decoder work-queue counter
#define F_GBAR    20640                    // MALL: prologue grid barrier
#define F_XCNT(x) (20672 + (x) * 32)       // MALL: per-XCD role counters

__device__ __forceinline__ unsigned short f2bf(float x) {  // RNE float->bf16
  union { float f; unsigned u; } v; v.f = x;
  unsigned r = v.u + 0x7FFFu + ((v.u >> 16) & 1u);
  return (unsigned short)(r >> 16);
}
__device__ __forceinline__ float sigm(float x) { return 1.f / (1.f + __expf(-x)); }

// L2-local flag add: no sc bits -> RMW executes at the issuing XCD's L2.
__device__ __forceinline__ void l2_add(unsigned* p) {
  unsigned one = 1u;
  asm volatile("global_atomic_add %0, %1, off" :: "v"(p), "v"(one) : "memory");
}
// L2-served poll load: sc0 bypasses L1, hits this XCD's L2 (sees local dirty line).
__device__ __forceinline__ unsigned l2_load(unsigned* p) {
  unsigned r;
  asm volatile("global_load_dword %0, %1, off sc0\n\ts_waitcnt vmcnt(0)"
               : "=v"(r) : "v"(p) : "memory");
  return r;
}
__device__ __forceinline__ unsigned mall_load(unsigned* p) {
  return __hip_atomic_load(p, __ATOMIC_RELAXED, __HIP_MEMORY_SCOPE_AGENT);
}
__device__ __forceinline__ void mall_add(unsigned* p) {
  (void)__hip_atomic_fetch_add(p, 1u, __ATOMIC_RELAXED, __HIP_MEMORY_SCOPE_AGENT);
}
__device__ __forceinline__ void vm_drain() {
  asm volatile("s_waitcnt vmcnt(0)" ::: "memory");
}

// Dual wait: burst of 8 local polls, then one MALL backup poll. If local
// signaling works, detect via the cheap path; if not, the MALL flag (posted at
// the same point, data equally drained) guarantees forward progress.
__device__ __forceinline__ void wait_h(unsigned* fl, unsigned* fm, bool fast) {
  if (fast) {
    while (true) {
      bool hit = false;
#pragma unroll
      for (int i = 0; i < 8; ++i) {
        if (l2_load(fl) >= 32u) { hit = true; break; }
        __builtin_amdgcn_s_sleep(1);
      }
      if (hit) break;
      if (mall_load(fm) >= 32u) break;
    }
  } else {
    while (mall_load(fm) < 32u) __builtin_amdgcn_s_sleep(2);
  }
  asm volatile("" ::: "memory");
}
template <int SLP>
__device__ __forceinline__ void waitflag(unsigned* f) {   // MALL-only edges
  while (mall_load(f) < 32u) __builtin_amdgcn_s_sleep(SLP);
  asm volatile("" ::: "memory");
}

struct KArgs {
  const int* x; const float* emb;
  const float* Wih1; const float* Whh1; const float* bi1; const float* bh1;
  const float* g1; const float* be1; const float* m1;
  const float* Wih2; const float* Whh2; const float* bi2; const float* bh2;
  const float* g2; const float* be2; const float* m2;
  const float* Wdec; const float* bdec;
  unsigned short* xs; unsigned short* wp; unsigned short* wdec; float* bias;
  unsigned short* h1q; unsigned short* abq; unsigned short* h2q; unsigned short* bseq;
  unsigned* bar; float* out;
};

// ---------------- single fused cooperative kernel ----------------
// 256 blocks x 256, 128KB LDS -> exactly 1 block/CU -> exactly 32 blocks/XCD.
// FAST mode (validated at runtime): XCD0 = layer-0, XCD1 = layer-1 via
// HW_REG_XCC_ID; the serial LSTM chain runs inside one XCD (plain stores +
// write-once plain loads + L2-executed atomics, ~300cyc hops). Cross-XCD edges
// (ab handoff, bseq->decoder) keep the sc1/MALL protocol (>= half-step slack).
// FALLBACK mode (role counters short, or local polls dead): bid-based roles +
// full MALL protocol == round-4 behavior, known-correct.
__global__ void __launch_bounds__(256, 1) k_main(KArgs a) {
  __shared__ unsigned short wlds[32 * 4 * 64 * 8];   // 128 KB: weight strip, frag order
  __shared__ float red[4][2][16];                    // BN cross-wave partials
  __shared__ int role_s, lb_s;

  unsigned* bar = a.bar;
  const int bid = blockIdx.x;
  const int lane = threadIdx.x & 63, w = threadIdx.x >> 6;
  const int q = lane >> 4, n = lane & 15;

  // ---- role claim by XCD (validated after the grid barrier) ----
  if (threadIdx.x == 0) {
    unsigned xcc;
    asm volatile("s_getreg_b32 %0, hwreg(HW_REG_XCC_ID)" : "=s"(xcc));
    xcc &= 7u;
    unsigned slot = __hip_atomic_fetch_add(bar + F_XCNT(xcc), 1u,
                                           __ATOMIC_RELAXED, __HIP_MEMORY_SCOPE_AGENT);
    int role = 2, lb = 0;
    if (slot < 32u) {
      if (xcc == 0u) { role = 0; lb = (int)slot; }
      else if (xcc == 1u) { role = 1; lb = (int)slot; }
    }
    role_s = role; lb_s = lb;
  }

  // ---------------- Phase A: prep (grid-stride over 65536 threads) ----------
  {
    const int gtid = bid * 256 + threadIdx.x;
    if (gtid < 4096)
      a.bias[gtid] = (gtid < NG) ? (a.bi1[gtid] + a.bh1[gtid])
                                 : (a.bi2[gtid - NG] + a.bh2[gtid - NG]);
    if (gtid < 4096) {
      ((uint4*)a.h1q)[gtid] = (uint4){0, 0, 0, 0};
      ((uint4*)a.h2q)[gtid] = (uint4){0, 0, 0, 0};
    }
    for (int i = gtid; i < 524288; i += 65536) {   // xs gather -> bf16
      int t = i >> 12, b = (i >> 6) & 63, h8 = i & 63;
      const float* src = a.emb + (size_t)a.x[b * 129 + t] * NH + h8 * 8;
      float4 u = *(const float4*)src, v = *(const float4*)(src + 4);
      unsigned short tmp[8] = {f2bf(u.x), f2bf(u.y), f2bf(u.z), f2bf(u.w),
                               f2bf(v.x), f2bf(v.y), f2bf(v.z), f2bf(v.w)};
      *(uint4*)(a.xs + (size_t)i * 8) = *(const uint4*)tmp;
    }
    for (int i = gtid; i < 516096; i += 65536) {   // wdec -> bf16, pad
      int v = i >> 6, h8 = i & 63;
      unsigned short tmp[8] = {0, 0, 0, 0, 0, 0, 0, 0};
      if (v < NV) {
        const float* src = a.Wdec + (size_t)v * NH + h8 * 8;
        float4 u = *(const float4*)src, vv = *(const float4*)(src + 4);
        tmp[0] = f2bf(u.x); tmp[1] = f2bf(u.y); tmp[2] = f2bf(u.z); tmp[3] = f2bf(u.w);
        tmp[4] = f2bf(vv.x); tmp[5] = f2bf(vv.y); tmp[6] = f2bf(vv.z); tmp[7] = f2bf(vv.w);
      }
      *(uint4*)(a.wdec + (size_t)i * 8) = *(const uint4*)tmp;
    }
    for (int i = gtid; i < 524288; i += 65536) {   // wpack frag order
      int l = i & 63, g = (i >> 6) & 3, s = (i >> 8) & 31, lb = (i >> 13) & 31, layer = i >> 18;
      int nn = l & 15, qq = l >> 4;
      int r = g * NH + lb * 16 + nn;
      int k0 = s * 32 + qq * 8;
      const float* Wih = layer ? a.Wih2 : a.Wih1;
      const float* Whh = layer ? a.Whh2 : a.Whh1;
      const float* src = (k0 < NH) ? (Wih + (size_t)r * NH + k0) : (Whh + (size_t)r * NH + (k0 - NH));
      unsigned short tmp[8];
#pragma unroll
      for (int j = 0; j < 8; ++j) tmp[j] = f2bf(src[j]);
      *(uint4*)(a.wp + (size_t)i * 8) = *(const uint4*)tmp;
    }
  }
  // grid barrier: leader release-fence publishes prep stores (wbL2 -> MALL)
  __syncthreads();
  if (threadIdx.x == 0) {
    __builtin_amdgcn_fence(__ATOMIC_RELEASE, "agent");
    mall_add(bar + F_GBAR);
    while (mall_load(bar + F_GBAR) < 256u) __builtin_amdgcn_s_sleep(8);
  }
  __syncthreads();
  asm volatile("" ::: "memory");

  // ---- validate the XCD mapping; choose protocol ----
  const bool fastlocal = (mall_load(bar + F_XCNT(0)) >= 32u) &&
                         (mall_load(bar + F_XCNT(1)) >= 32u);
  int role, lb;
  if (fastlocal) { role = role_s; lb = lb_s; }
  else           { role = (bid < 64) ? (bid >> 5) : 2; lb = bid & 31; }

  // ---------------- Phase B: recurrence ------------------------------------
  if (role < 2) {
    const int layer = role, f0 = lb * 16;
    const float* gam = layer ? a.g2 : a.g1;
    const float* bet = layer ? a.be2 : a.be1;
    const float* msk = layer ? a.m2 : a.m1;
    const float* bias_l = a.bias + layer * NG;
    unsigned* fL = bar + (layer ? F_H2L(0) : F_H1L(0));
    unsigned* fM = bar + (layer ? F_H2M(0) : F_H1M(0));

    { // stage weights -> LDS (strip selected by ROLE)
      const uint4* src = (const uint4*)(a.wp + (size_t)(layer * 32 + lb) * (32 * 4 * 64 * 8));
      uint4* dst = (uint4*)wlds;
      for (int i = threadIdx.x; i < 32 * 4 * 64; i += 256) dst[i] = src[i];
    }
    __syncthreads();

    const int m0 = w * 16;
    const float gmv = gam[f0 + n], btv = bet[f0 + n];
    float bias_g[4], mk[4];
#pragma unroll
    for (int g = 0; g < 4; ++g) bias_g[g] = bias_l[g * NH + f0 + n];
#pragma unroll
    for (int r = 0; r < 4; ++r) mk[r] = msk[(m0 + q * 4 + r) * NH + f0 + n];

    float cst[4] = {0.f, 0.f, 0.f, 0.f};

    for (int t = 0; t < NSTEP; ++t) {
      f32x4 acc[4];
#pragma unroll
      for (int g = 0; g < 4; ++g) acc[g] = (f32x4){bias_g[g], bias_g[g], bias_g[g], bias_g[g]};

      if (layer == 0) {
        // xs-half first: no dependency -> overlaps the wait for peers' h1
        const unsigned short* rowA0 = a.xs + (size_t)t * SLAB + (m0 + n) * NH;
#pragma unroll
        for (int s = 0; s < 16; ++s) {
          bf16x8 af = *(const bf16x8*)(rowA0 + s * 32 + q * 8);
#pragma unroll
          for (int g = 0; g < 4; ++g)
            acc[g] = __builtin_amdgcn_mfma_f32_16x16x32_bf16(
                af, *(const bf16x8*)&wlds[((s * 4 + g) * 64 + lane) * 8], acc[g], 0, 0, 0);
        }
        if (t > 0) wait_h(fL + (t - 1) * 32, fM + (t - 1) * 32, fastlocal);
        const unsigned short* rowA1 = a.h1q + (size_t)t * SLAB + (m0 + n) * NH;
#pragma unroll
        for (int s = 0; s < 16; ++s) {
          bf16x8 af = *(const bf16x8*)(rowA1 + s * 32 + q * 8);
#pragma unroll
          for (int g = 0; g < 4; ++g)
            acc[g] = __builtin_amdgcn_mfma_f32_16x16x32_bf16(
                af, *(const bf16x8*)&wlds[(((s + 16) * 4 + g) * 64 + lane) * 8], acc[g], 0, 0, 0);
        }
      } else {
        if (t > 0) wait_h(fL + (t - 1) * 32, fM + (t - 1) * 32, fastlocal);
        const unsigned short* rowA1 = a.h2q + (size_t)t * SLAB + (m0 + n) * NH;
#pragma unroll
        for (int s = 0; s < 16; ++s) {
          bf16x8 af = *(const bf16x8*)(rowA1 + s * 32 + q * 8);
#pragma unroll
          for (int g = 0; g < 4; ++g)
            acc[g] = __builtin_amdgcn_mfma_f32_16x16x32_bf16(
                af, *(const bf16x8*)&wlds[(((s + 16) * 4 + g) * 64 + lane) * 8], acc[g], 0, 0, 0);
        }
        waitflag<2>(bar + F_AB(t));                     // ab[t] published (MALL)
        const unsigned short* rowA0 = a.abq + (size_t)t * SLAB + (m0 + n) * NH;
#pragma unroll
        for (int s = 0; s < 16; ++s) {
          bf16x8 af = *(const bf16x8*)(rowA0 + s * 32 + q * 8);
#pragma unroll
          for (int g = 0; g < 4; ++g)
            acc[g] = __builtin_amdgcn_mfma_f32_16x16x32_bf16(
                af, *(const bf16x8*)&wlds[((s * 4 + g) * 64 + lane) * 8], acc[g], 0, 0, 0);
        }
      }

      // LSTM cell (gate order i,f,g,o), all lane-local
      float hv[4], sum = 0.f, ssq = 0.f;
#pragma unroll
      for (int r = 0; r < 4; ++r) {
        float ig = sigm(acc[0][r]), fg = sigm(acc[1][r]);
        float gg = tanhf(acc[2][r]), og = sigm(acc[3][r]);
        cst[r] = fg * cst[r] + ig * gg;
        hv[r] = og * tanhf(cst[r]);
        sum += hv[r]; ssq += hv[r] * hv[r];
      }
      // h doesn't depend on BN: store NOW. FAST: plain (lands in local L2).
      // FALLBACK: sc1 write-through (lands at MALL). Drained before S1.
      unsigned short* hout = ((layer == 0) ? a.h1q : a.h2q) + (size_t)(t + 1) * SLAB;
#pragma unroll
      for (int r = 0; r < 4; ++r) {
        unsigned short hb = f2bf(hv[r]);
        if (fastlocal) hout[(m0 + q * 4 + r) * NH + f0 + n] = hb;
        else __hip_atomic_store(&hout[(m0 + q * 4 + r) * NH + f0 + n], hb,
                                __ATOMIC_RELAXED, __HIP_MEMORY_SCOPE_AGENT);
      }

      // batch stats for feature f0+n: reduce over q (shfl) then waves (LDS)
      sum += __shfl_xor(sum, 16); ssq += __shfl_xor(ssq, 16);
      sum += __shfl_xor(sum, 32); ssq += __shfl_xor(ssq, 32);
      if (q == 0) { red[w][0][n] = sum; red[w][1][n] = ssq; }
      vm_drain();        // this wave's h stores acked (L2 in fast, MALL in fallback)
      __syncthreads();   // S1: all waves drained
      if (threadIdx.x == 0) {
        if (fastlocal) l2_add(fL + t * 32);   // cheap local signal
        mall_add(fM + t * 32);                // backup / fallback signal
      }

      float s1 = red[0][0][n] + red[1][0][n] + red[2][0][n] + red[3][0][n];
      float s2 = red[0][1][n] + red[1][1][n] + red[2][1][n] + red[3][1][n];
      float mu = s1 * (1.f / 64.f);
      float var = s2 * (1.f / 64.f) - mu * mu;
      float rs = rsqrtf(var + 1e-5f);

      // cross-XCD payload: ab (layer0) / bseq (layer1) via sc1 write-through
      unsigned short* aout = ((layer == 0) ? a.abq : a.bseq) + (size_t)t * SLAB;
#pragma unroll
      for (int r = 0; r < 4; ++r) {
        float bn = (hv[r] - mu) * rs * gmv + btv;
        __hip_atomic_store(&aout[(m0 + q * 4 + r) * NH + f0 + n], f2bf(bn * mk[r]),
                           __ATOMIC_RELAXED, __HIP_MEMORY_SCOPE_AGENT);
      }

      vm_drain();
      __syncthreads();   // S2: sc1 stores at MALL; also guards red[] reuse
      if (threadIdx.x == 0) {
        if (layer == 0) mall_add(bar + F_AB(t));
        else if ((t & 31) == 31) mall_add(bar + F_DC(t >> 5));
      }
    }
  }

  // ---------------- Phase C: decoder work queue (all blocks) -----------------
  // chunk c: tc = c>>12, r = c&4095 (skip r>=4032), nb = r>>6, b = r&63.
  while (true) {
    unsigned c = 0;
    if (lane == 0) c = atomicAdd(bar + F_QCNT, 1u);
    c = __shfl(c, 0);
    if (c >= 16384u) break;
    unsigned tc = c >> 12, r = c & 4095u;
    if (r >= 4032u) continue;
    int nb = (int)(r >> 6), b = (int)(r & 63u);
    waitflag<127>(bar + F_DC(tc));   // bseq[tc*32 .. tc*32+31] final (MALL)

    const int n0 = nb * 128;
    f32x4 acc[2][8];
#pragma unroll
    for (int nt = 0; nt < 8; ++nt) {
      int v = n0 + nt * 16 + n;
      float bd = (v < NV) ? a.bdec[v] : 0.f;
      acc[0][nt] = (f32x4){bd, bd, bd, bd};
      acc[1][nt] = acc[0][nt];
    }
    const unsigned short* arow[2];
#pragma unroll
    for (int mt = 0; mt < 2; ++mt)
      arow[mt] = a.bseq + ((size_t)(tc * 32 + mt * 16 + n) * NBATCH + b) * NH;
    const unsigned short* brow[8];
#pragma unroll
    for (int nt = 0; nt < 8; ++nt) brow[nt] = a.wdec + (size_t)(n0 + nt * 16 + n) * NH;

#pragma unroll 4
    for (int s = 0; s < 16; ++s) {
      bf16x8 af[2];
#pragma unroll
      for (int mt = 0; mt < 2; ++mt) af[mt] = *(const bf16x8*)(arow[mt] + s * 32 + q * 8);
#pragma unroll
      for (int nt = 0; nt < 8; ++nt) {
        bf16x8 bf = *(const bf16x8*)(brow[nt] + s * 32 + q * 8);
#pragma unroll
        for (int mt = 0; mt < 2; ++mt)
          acc[mt][nt] = __builtin_amdgcn_mfma_f32_16x16x32_bf16(af[mt], bf, acc[mt][nt], 0, 0, 0);
      }
    }
#pragma unroll
    for (int mt = 0; mt < 2; ++mt)
#pragma unroll
      for (int nt = 0; nt < 8; ++nt) {
        int v = n0 + nt * 16 + n;
        if (v < NV) {
          int t0 = (int)tc * 32 + mt * 16 + q * 4;
          *(f32x4*)(a.out + ((size_t)b * NV + v) * NSTEP + t0) = acc[mt][nt];
        }
      }
  }
}

// ---------------- launch ----------------
extern "C" void kernel_launch(void* const* d_in, const int* in_sizes, int n_in,
                              void* d_out, int out_size, void* d_ws, size_t ws_size,
                              hipStream_t stream) {
  char* ws = (char*)d_ws;

  KArgs a;
  a.x    = (const int*)d_in[0];
  a.emb  = (const float*)d_in[1];
  a.Wih1 = (const float*)d_in[2];
  a.Whh1 = (const float*)d_in[3];
  a.bi1  = (const float*)d_in[4];
  a.bh1  = (const float*)d_in[5];
  a.g1   = (const float*)d_in[6];
  a.be1  = (const float*)d_in[7];
  a.m1   = (const float*)d_in[8];
  a.Wih2 = (const float*)d_in[9];
  a.Whh2 = (const float*)d_in[10];
  a.bi2  = (const float*)d_in[11];
  a.bh2  = (const float*)d_in[12];
  a.g2   = (const float*)d_in[13];
  a.be2  = (const float*)d_in[14];
  a.m2   = (const float*)d_in[15];
  a.Wdec = (const float*)d_in[16];
  a.bdec = (const float*)d_in[17];
  a.xs   = (unsigned short*)(ws + OFF_XS);
  a.wp   = (unsigned short*)(ws + OFF_WP);
  a.wdec = (unsigned short*)(ws + OFF_WDEC);
  a.bias = (float*)(ws + OFF_BIAS);
  a.h1q  = (unsigned short*)(ws + OFF_H1);
  a.abq  = (unsigned short*)(ws + OFF_AB);
  a.h2q  = (unsigned short*)(ws + OFF_H2);
  a.bseq = (unsigned short*)(ws + OFF_BSEQ);
  a.bar  = (unsigned*)(ws + OFF_BAR);
  a.out  = (float*)d_out;

  // zero all flags (ws is poisoned 0xAA before every call)
  (void)hipMemsetAsync(a.bar, 0, SZ_BAR, stream);

  void* kargs[] = {(void*)&a};
  (void)hipLaunchCooperativeKernel((void*)k_main, dim3(256), dim3(256), kargs, 0, stream);
}